// Round 8
// baseline (247.977 us; speedup 1.0000x reference)
//
#include <hip/hip_runtime.h>

#define H    128
#define WP   130
#define BPF  516           // border pixels per face image
#define TBLN 3096          // 6 * 516
#define SPI  1536          // staged floats per image: 4*128 rows + 128*8 cols

// Face order: back(0), down(1), front(2), left(3), right(4), top(5)
__constant__ int c_R[6][9] = {
  {-1,0,0,  0,1,0,  0,0,-1},
  { 1,0,0,  0,0,-1, 0,1,0 },
  { 1,0,0,  0,1,0,  0,0,1 },
  { 0,0,1,  0,1,0, -1,0,0 },
  { 0,0,-1, 0,1,0,  1,0,0 },
  { 1,0,0,  0,0,1,  0,-1,0},
};
// NEIGHBORS[face][side], side order: up(0), down(1), left(2), right(3)
__constant__ int c_conn[6][4] = {
  {5,1,4,3}, {2,0,3,4}, {5,1,3,4}, {5,1,0,2}, {5,1,2,0}, {0,2,3,4},
};

#define INV_FP (65.0f / 4128.0f)

// Staging layout per image (SPI floats):
//   [0..511]    rows: slot*128 + x, slot: y=0->0, 1->1, 126->2, 127->3
//   [512..1535] cols: 512 + y*8 + cs, cs: x=0..3 -> 0..3, x=124..127 -> 4..7
__device__ __forceinline__ int stage_index(int y, int x) {
  if (x <= 3)   return 512 + y * 8 + x;
  if (x >= 124) return 512 + y * 8 + 4 + (x - 124);
  int slot = (y == 0) ? 0 : (y == 1) ? 1 : (y == 126) ? 2 : 3;
  return slot * 128 + x;
}

// ---------- kernel A: build border tables (raw + staged indices) ---------
__global__ void __launch_bounds__(256)
border_table_kernel(int* __restrict__ tb_face, int4* __restrict__ tb_raw,
                    int4* __restrict__ tb_stg, float4* __restrict__ tb_w) {
  int t = blockIdx.x * 256 + threadIdx.x;
  if (t >= TBLN) return;
  int face = t / BPF;
  int k    = t - face * BPF;

  int r, c;
  if (k < 130)      { r = 0;        c = k; }
  else if (k < 260) { r = WP - 1;   c = k - 130; }
  else if (k < 388) { r = k - 259;  c = 0; }
  else              { r = k - 387;  c = WP - 1; }

  int fs = -1;
  int4  raw = make_int4(0, 0, 0, 0);
  int4  stg = make_int4(0, 0, 0, 0);
  float4 w  = make_float4(0.f, 0.f, 0.f, 0.f);

  int cand[2]; int nc = 0;
  if (c == WP - 1) cand[nc++] = 3;
  if (c == 0)      cand[nc++] = 2;
  if (r == WP - 1) cand[nc++] = 1;
  if (r == 0)      cand[nc++] = 0;

  float uc = ((float)c - 64.5f) * INV_FP;
  float ur = ((float)r - 64.5f) * INV_FP;

  for (int kk = 0; kk < nc; ++kk) {
    int s  = cand[kk];
    int cf = c_conn[face][s];
    const int* Rc = c_R[cf];
    const int* Rf = c_R[face];
    float g[3];
    #pragma unroll
    for (int i = 0; i < 3; ++i) {
      float acc = 0.0f;
      #pragma unroll
      for (int j = 0; j < 3; ++j) {
        int rr = Rc[i*3+0]*Rf[j*3+0] + Rc[i*3+1]*Rf[j*3+1] + Rc[i*3+2]*Rf[j*3+2];
        float dj = (j == 0) ? uc : (j == 1) ? ur : 1.0f;
        acc += (float)rr * dj;
      }
      g[i] = acc;
    }
    float x = g[0] / g[2];
    float y = g[1] / g[2];
    if (fabsf(x) <= 1.01f && fabsf(y) <= 1.01f) {
      x = fminf(fmaxf(x, -1.0f), 1.0f);
      y = fminf(fmaxf(y, -1.0f), 1.0f);
      float xp = (x + 1.0f) * 0.5f * (float)(H - 1);
      float yp = (y + 1.0f) * 0.5f * (float)(H - 1);
      float x0 = floorf(xp), y0 = floorf(yp);
      float wx = xp - x0,    wy = yp - y0;
      int x0i = min(max((int)x0, 0), H - 1);
      int x1i = min(x0i + 1, H - 1);
      int y0i = min(max((int)y0, 0), H - 1);
      int y1i = min(y0i + 1, H - 1);
      fs  = cf;
      raw = make_int4(y0i * H + x0i, y0i * H + x1i, y1i * H + x0i, y1i * H + x1i);
      stg = make_int4(stage_index(y0i, x0i), stage_index(y0i, x1i),
                      stage_index(y1i, x0i), stage_index(y1i, x1i));
      w   = make_float4((1.f - wx) * (1.f - wy), wx * (1.f - wy),
                        (1.f - wx) * wy,         wx * wy);
      break;
    }
  }
  tb_face[t] = fs;
  tb_raw[t]  = raw;
  tb_stg[t]  = stg;
  tb_w[t]    = w;
}

// ---------- kernel B: bulk row-pair copy + strip staging ------------------
// Lane l of 32-group hh loads input quad A = in4[img*4096 + 32*hh + l]
// (each input quad read exactly once), neighbor via __shfl_down, stores one
// aligned output quad. Lanes 0/31 also dump A into the per-image strip
// staging; groups for rows {0,1,126,127} dump the full row.
__global__ void __launch_bounds__(256)
bulk_stage_kernel(const float* __restrict__ in, float4* __restrict__ out4,
                  float* __restrict__ stage) {
  const unsigned bx  = blockIdx.x;        // 0..15
  const unsigned img = blockIdx.y;
  const unsigned u   = threadIdx.x;

  unsigned hh = (bx << 3) + (u >> 5);     // input row 0..127
  unsigned l  = u & 31u;
  unsigned g  = hh + 1u;                  // output row 1..128
  unsigned m  = g >> 1;                   // row-pair
  unsigned h  = g & 1u;

  const float4* base = (const float4*)in + ((size_t)img << 12);
  float4 A = base[(hh << 5) + l];
  float bx0 = __shfl_down(A.x, 1, 32);
  float by0 = __shfl_down(A.y, 1, 32);
  float bz0 = __shfl_down(A.z, 1, 32);

  float4 o = h ? make_float4(A.y, A.z, A.w, bx0)
               : make_float4(A.w, bx0, by0, bz0);
  if (l < 31u)
    out4[(size_t)img * 4225u + 65u * m + 1u + (h << 5) + l] = o;

  // ---- strip staging (from registers; input read once) ----
  float* simg = stage + (size_t)img * SPI;
  if (l == 0u)  *(float4*)(simg + 512u + hh * 8u)      = A;  // cols 0..3
  if (l == 31u) *(float4*)(simg + 512u + hh * 8u + 4u) = A;  // cols 124..127
  if (hh == 0u || hh == 1u || hh == 126u || hh == 127u) {
    unsigned slot = (hh == 0u) ? 0u : (hh == 1u) ? 1u : (hh == 126u) ? 2u : 3u;
    *(float4*)(simg + slot * 128u + (l << 2)) = A;           // full row
  }
}

// ---------- kernel C: edge quads (257/img) — all reads from staging ------
__global__ void __launch_bounds__(256)
edge_stage_kernel(float4* __restrict__ out4, const float* __restrict__ stage,
                  const int* __restrict__ tb_face,
                  const int4* __restrict__ tb_stg,
                  const float4* __restrict__ tb_w) {
  const unsigned img = blockIdx.x;
  const unsigned u   = threadIdx.x;

  unsigned n    = img >> 8;
  unsigned ch   = img & 255u;
  unsigned rep  = n / 6u;
  unsigned face = n - rep * 6u;
  const float* simg = stage + (size_t)img * SPI;

  for (unsigned k = u; k < 257u; k += 256u) {
    unsigned qk;
    if (k < 33u)       qk = k;                     // pair 0: q 0..32
    else if (k == 33u) qk = 64u;                   // pair 0: q 64
    else if (k == 34u) qk = 4160u;                 // pair 64: q 0
    else if (k < 68u)  qk = 4192u + (k - 35u);     // pair 64: q 32..64
    else {
      unsigned jj = k - 68u;                       // 0..188
      unsigned mm = 1u + jj / 3u;                  // 1..63
      unsigned w  = jj - 3u * (jj / 3u);           // 0,1,2
      qk = 65u * mm + ((w == 0u) ? 0u : (w == 1u) ? 32u : 64u);
    }

    unsigned p = qk << 2;
    unsigned r = p / 130u;
    unsigned c = p - r * 130u;
    float vals[4];
    #pragma unroll
    for (int jj = 0; jj < 4; ++jj) {
      float v;
      if ((r - 1u) < 128u && (c - 1u) < 128u) {
        unsigned cc = c - 1u;                      // in {0,1,2,125,126,127}
        unsigned cs = (cc < 4u) ? cc : (cc - 120u);
        v = simg[512u + (r - 1u) * 8u + cs];
      } else {
        unsigned tk = (r == 0u)   ? c
                    : (r == 129u) ? (130u + c)
                    : (c == 0u)   ? (259u + r)
                    :               (387u + r);
        unsigned ti = face * (unsigned)BPF + tk;
        int fs = tb_face[ti];
        v = 0.0f;
        if (fs >= 0) {
          int4   id = tb_stg[ti];
          float4 w  = tb_w[ti];
          const float* sj = stage +
              (size_t)(((rep * 6u + (unsigned)fs) << 8) + ch) * SPI;
          v = w.x * sj[id.x] + w.y * sj[id.y] + w.z * sj[id.z] + w.w * sj[id.w];
        }
      }
      vals[jj] = v;
      if (++c == 130u) { c = 0u; ++r; }
    }
    out4[(size_t)img * 4225u + qk] =
        make_float4(vals[0], vals[1], vals[2], vals[3]);
  }
}

// ---------- tier-2 fallback: R7 fused kernel (raw-index table) -----------
__global__ void __launch_bounds__(256)
fused_kernel(const float* __restrict__ in, float4* __restrict__ out4,
             const int* __restrict__ tb_face,
             const int4* __restrict__ tb_idx,
             const float4* __restrict__ tb_w) {
  const unsigned bx  = blockIdx.x;
  const unsigned img = blockIdx.y;
  const unsigned u   = threadIdx.x;

  if (bx < 16u) {
    unsigned hh = (bx << 3) + (u >> 5);
    unsigned l  = u & 31u;
    unsigned g  = hh + 1u;
    unsigned m  = g >> 1;
    unsigned h  = g & 1u;

    const float4* base = (const float4*)in + ((size_t)img << 12);
    float4 A = base[(hh << 5) + l];
    float bx0 = __shfl_down(A.x, 1, 32);
    float by0 = __shfl_down(A.y, 1, 32);
    float bz0 = __shfl_down(A.z, 1, 32);

    float4 o = h ? make_float4(A.y, A.z, A.w, bx0)
                 : make_float4(A.w, bx0, by0, bz0);
    if (l < 31u)
      out4[(size_t)img * 4225u + 65u * m + 1u + (h << 5) + l] = o;
  } else {
    unsigned n    = img >> 8;
    unsigned ch   = img & 255u;
    unsigned rep  = n / 6u;
    unsigned face = n - rep * 6u;

    for (unsigned k = u; k < 257u; k += 256u) {
      unsigned qk;
      if (k < 33u)       qk = k;
      else if (k == 33u) qk = 64u;
      else if (k == 34u) qk = 4160u;
      else if (k < 68u)  qk = 4192u + (k - 35u);
      else {
        unsigned jj = k - 68u;
        unsigned mm = 1u + jj / 3u;
        unsigned w  = jj - 3u * (jj / 3u);
        qk = 65u * mm + ((w == 0u) ? 0u : (w == 1u) ? 32u : 64u);
      }

      unsigned p = qk << 2;
      unsigned r = p / 130u;
      unsigned c = p - r * 130u;
      float vals[4];
      #pragma unroll
      for (int jj = 0; jj < 4; ++jj) {
        float v;
        if ((r - 1u) < 128u && (c - 1u) < 128u) {
          v = in[(img << 14) + ((r - 1u) << 7) + (c - 1u)];
        } else {
          unsigned tk = (r == 0u)   ? c
                      : (r == 129u) ? (130u + c)
                      : (c == 0u)   ? (259u + r)
                      :               (387u + r);
          unsigned ti = face * (unsigned)BPF + tk;
          int fs = tb_face[ti];
          v = 0.0f;
          if (fs >= 0) {
            int4   id = tb_idx[ti];
            float4 w  = tb_w[ti];
            const float* s = in +
                ((size_t)(((rep * 6u + (unsigned)fs) << 8) + ch) << 14);
            v = w.x * s[id.x] + w.y * s[id.y] + w.z * s[id.z] + w.w * s[id.w];
          }
        }
        vals[jj] = v;
        if (++c == 130u) { c = 0u; ++r; }
      }
      out4[(size_t)img * 4225u + qk] =
          make_float4(vals[0], vals[1], vals[2], vals[3]);
    }
  }
}

// ---------- tier-3 fallback: round-2 simple kernels -----------------------
__global__ void __launch_bounds__(256)
interior_kernel(const float4* __restrict__ in4, float* __restrict__ out) {
  unsigned t = blockIdx.x * 256u + threadIdx.x;
  unsigned c4  = t & 31u;
  unsigned r   = (t >> 5) & 127u;
  unsigned img = t >> 12;
  float4 v = in4[t];
  unsigned o = img * 16900u + (r + 1u) * 130u + 1u + (c4 << 2);
  out[o] = v.x; out[o + 1] = v.y; out[o + 2] = v.z; out[o + 3] = v.w;
}

__global__ void __launch_bounds__(256)
border_kernel(const float* __restrict__ in, float* __restrict__ out) {
  unsigned tid = blockIdx.x * 256u + threadIdx.x;
  const unsigned total = 6144u * 516u;
  if (tid >= total) return;
  unsigned img = tid / 516u;
  unsigned k   = tid - img * 516u;
  int r, c;
  if (k < 130u)      { r = 0;               c = (int)k; }
  else if (k < 260u) { r = WP - 1;          c = (int)(k - 130u); }
  else if (k < 388u) { r = (int)(k - 259u); c = 0; }
  else               { r = (int)(k - 387u); c = WP - 1; }
  int n = (int)(img >> 8), ch = (int)(img & 255u);
  int face = n % 6, rep = n / 6;
  float v = 0.0f;
  int cand[2]; int nc = 0;
  if (c == WP - 1) cand[nc++] = 3;
  if (c == 0)      cand[nc++] = 2;
  if (r == WP - 1) cand[nc++] = 1;
  if (r == 0)      cand[nc++] = 0;
  float uc = ((float)c - 64.5f) * INV_FP;
  float ur = ((float)r - 64.5f) * INV_FP;
  for (int kk = 0; kk < nc; ++kk) {
    int s = cand[kk], cf = c_conn[face][s];
    const int* Rc = c_R[cf]; const int* Rf = c_R[face];
    float g[3];
    #pragma unroll
    for (int i = 0; i < 3; ++i) {
      float acc = 0.0f;
      #pragma unroll
      for (int j = 0; j < 3; ++j) {
        int rr = Rc[i*3+0]*Rf[j*3+0] + Rc[i*3+1]*Rf[j*3+1] + Rc[i*3+2]*Rf[j*3+2];
        float dj = (j == 0) ? uc : (j == 1) ? ur : 1.0f;
        acc += (float)rr * dj;
      }
      g[i] = acc;
    }
    float x = g[0] / g[2], y = g[1] / g[2];
    if (fabsf(x) <= 1.01f && fabsf(y) <= 1.01f) {
      x = fminf(fmaxf(x, -1.0f), 1.0f);
      y = fminf(fmaxf(y, -1.0f), 1.0f);
      const float* src = in + ((size_t)((rep * 6 + cf) * 256 + ch)) * H * H;
      float xp = (x + 1.0f) * 0.5f * (float)(H - 1);
      float yp = (y + 1.0f) * 0.5f * (float)(H - 1);
      float x0 = floorf(xp), y0 = floorf(yp);
      float wx = xp - x0, wy = yp - y0;
      int x0i = min(max((int)x0, 0), H - 1);
      int x1i = min(x0i + 1, H - 1);
      int y0i = min(max((int)y0, 0), H - 1);
      int y1i = min(y0i + 1, H - 1);
      v = src[y0i*H+x0i]*(1.f-wx)*(1.f-wy) + src[y0i*H+x1i]*wx*(1.f-wy)
        + src[y1i*H+x0i]*(1.f-wx)*wy       + src[y1i*H+x1i]*wx*wy;
      break;
    }
  }
  out[(unsigned)img * 16900u + (unsigned)r * 130u + (unsigned)c] = v;
}

extern "C" void kernel_launch(void* const* d_in, const int* in_sizes, int n_in,
                              void* d_out, int out_size, void* d_ws, size_t ws_size,
                              hipStream_t stream) {
  (void)in_sizes; (void)n_in; (void)out_size;
  const float* in = (const float*)d_in[0];
  float* out = (float*)d_out;

  const size_t tbl_bytes  = (size_t)TBLN * (4 + 16 + 16 + 16);        // 160,992
  const size_t need_full  = tbl_bytes + (size_t)6144 * SPI * 4;       // ~37.9 MB

  if (d_ws != nullptr && ws_size >= tbl_bytes) {
    int*    tb_face = (int*)d_ws;
    int4*   tb_raw  = (int4*)(tb_face + TBLN);
    int4*   tb_stg  = tb_raw + TBLN;
    float4* tb_w    = (float4*)(tb_stg + TBLN);
    border_table_kernel<<<(TBLN + 255) / 256, 256, 0, stream>>>(
        tb_face, tb_raw, tb_stg, tb_w);

    if (ws_size >= need_full) {
      float* stage = (float*)(tb_w + TBLN);
      dim3 gridB(16, 6144);
      bulk_stage_kernel<<<gridB, 256, 0, stream>>>(in, (float4*)out, stage);
      edge_stage_kernel<<<6144, 256, 0, stream>>>((float4*)out, stage,
                                                  tb_face, tb_stg, tb_w);
    } else {
      dim3 grid(17, 6144);
      fused_kernel<<<grid, 256, 0, stream>>>(in, (float4*)out,
                                             tb_face, tb_raw, tb_w);
    }
  } else {
    interior_kernel<<<98304, 256, 0, stream>>>((const float4*)in, out);
    const unsigned btotal = 6144u * 516u;
    border_kernel<<<(btotal + 255u) / 256u, 256, 0, stream>>>(in, out);
  }
}